// Round 1
// baseline (385.062 us; speedup 1.0000x reference)
//
#include <hip/hip_runtime.h>

// Problem constants
#define Bb 2
#define Ss 2048
#define Dd 1024
#define Hh 16
#define DKk 64
#define Mm (Bb*Ss)          // 4096 rows in all GEMMs

typedef __bf16 bf16;
typedef __attribute__((ext_vector_type(8))) __bf16 bf16x8;
typedef __attribute__((ext_vector_type(4))) __bf16 bf16x4;
typedef __attribute__((ext_vector_type(4))) float  f32x4;

#define MFMA(Af, Bf, Cf) __builtin_amdgcn_mfma_f32_16x16x32_bf16(Af, Bf, Cf, 0, 0, 0)

__device__ __forceinline__ void gld_lds16(const void* g, void* l) {
  __builtin_amdgcn_global_load_lds(
      (const __attribute__((address_space(1))) void*)g,
      (__attribute__((address_space(3))) void*)l, 16, 0, 0);
}

// ---------------------------------------------------------------- convert
__global__ __launch_bounds__(256) void cvt_f32_bf16(
    const float* __restrict__ s, bf16* __restrict__ d, int n4) {
  int i = blockIdx.x * 256 + threadIdx.x;
  if (i >= n4) return;
  float4 v = reinterpret_cast<const float4*>(s)[i];
  bf16x4 o;
  o[0] = (bf16)v.x; o[1] = (bf16)v.y; o[2] = (bf16)v.z; o[3] = (bf16)v.w;
  reinterpret_cast<bf16x4*>(d)[i] = o;
}

// ---------------------------------------------------------------- GEMM (B^T)
// C[i,j] = sum_k A[i,k] * W[j,k] + bias[j]      M=4096, N=1024, K=1024
// 128x128 tile, BK=32, 256 threads = 4 waves (2x2), global_load_lds staging.
template <bool F32OUT>
__global__ __launch_bounds__(256) void gemm_bt(
    const bf16* __restrict__ A, const bf16* __restrict__ W,
    const float* __restrict__ bias, bf16* __restrict__ out_bf,
    float* __restrict__ out_f32) {
  constexpr int N = 1024, K = 1024;
  __shared__ bf16 As[128 * 32];
  __shared__ bf16 Bs[128 * 32];
  const int tid = threadIdx.x;
  const int w = tid >> 6, lane = tid & 63;
  const int wr = w >> 1, wc = w & 1;
  const int row0 = blockIdx.y * 128, col0 = blockIdx.x * 128;
  const bf16* Ab = A + (size_t)row0 * K;
  const bf16* Wb = W + (size_t)col0 * K;

  f32x4 acc[4][4] = {};

  for (int kt = 0; kt < K / 32; ++kt) {
    const int k0 = kt * 32;
    // stage A and B tiles: 8KB each, 8 wave-instrs each (2 per wave)
#pragma unroll
    for (int i = 0; i < 2; ++i) {
      const int c = i * 4 + w;                 // 1KB chunk id
      const int r = c * 16 + (lane >> 2);      // tile row
      const int ce = (lane & 3) * 8;           // k element offset within BK
      gld_lds16(Ab + (size_t)r * K + k0 + ce, (char*)As + c * 1024);
      gld_lds16(Wb + (size_t)r * K + k0 + ce, (char*)Bs + c * 1024);
    }
    __syncthreads();

    bf16x8 af[4], bfr[4];
#pragma unroll
    for (int m = 0; m < 4; ++m) {
      const int r = wr * 64 + m * 16 + (lane & 15);
      af[m] = *(const bf16x8*)&As[r * 32 + (lane >> 4) * 8];
    }
#pragma unroll
    for (int n = 0; n < 4; ++n) {
      const int r = wc * 64 + n * 16 + (lane & 15);
      bfr[n] = *(const bf16x8*)&Bs[r * 32 + (lane >> 4) * 8];
    }
#pragma unroll
    for (int m = 0; m < 4; ++m)
#pragma unroll
      for (int n = 0; n < 4; ++n)
        acc[m][n] = MFMA(af[m], bfr[n], acc[m][n]);
    __syncthreads();
  }

  // epilogue: C/D layout col=lane&15, row=(lane>>4)*4+r
  const int g = lane >> 4, c15 = lane & 15;
#pragma unroll
  for (int n = 0; n < 4; ++n) {
    const int col = col0 + wc * 64 + n * 16 + c15;
    const float bv = bias[col];
#pragma unroll
    for (int m = 0; m < 4; ++m) {
      const int rbase = row0 + wr * 64 + m * 16 + g * 4;
#pragma unroll
      for (int r = 0; r < 4; ++r) {
        const float v = acc[m][n][r] + bv;
        if (F32OUT) out_f32[(size_t)(rbase + r) * N + col] = v;
        else        out_bf [(size_t)(rbase + r) * N + col] = (bf16)v;
      }
    }
  }
}

// ---------------------------------------------------------------- attention
// One block = 64 q-rows of one (b,h). 4 waves, 16 q-rows each.
// K staged [2(ks=d-half)][64 kv][32 d]  (linear for global_load_lds, conflict-free reads)
// V staged transposed [2(kh=kv-half)][64 d][32 kv]
__global__ __launch_bounds__(256) void attn_fwd(
    const bf16* __restrict__ Q, const bf16* __restrict__ K,
    const bf16* __restrict__ V, bf16* __restrict__ X) {
  __shared__ bf16 Ks[2][64][32];
  __shared__ bf16 Vs[2][64][32];
  __shared__ bf16 Ps[4][16][64];

  const int tid = threadIdx.x;
  const int w = tid >> 6, lane = tid & 63;
  const int bh = blockIdx.y, b = bh >> 4, h = bh & 15;
  const int qt = blockIdx.x, q0 = qt * 64;

  const bf16* Qb = Q + (size_t)b * Ss * Dd + h * DKk;
  const bf16* Kb = K + (size_t)b * Ss * Dd + h * DKk;
  const bf16* Vb = V + (size_t)b * Ss * Dd + h * DKk;

  // Q fragments in registers: rows q0+w*16+(lane&15), k=d contiguous
  bf16x8 qf[2];
  {
    const int qr = q0 + w * 16 + (lane & 15);
    const int d0 = (lane >> 4) * 8;
    qf[0] = *(const bf16x8*)&Qb[(size_t)qr * Dd + d0];
    qf[1] = *(const bf16x8*)&Qb[(size_t)qr * Dd + d0 + 32];
  }

  f32x4 of[4] = {};
  float m_run[4], l_run[4];
#pragma unroll
  for (int r = 0; r < 4; ++r) { m_run[r] = -INFINITY; l_run[r] = 0.f; }

  const int nchunks = qt + 1;
  for (int ct = 0; ct < nchunks; ++ct) {
    const int kv0 = ct * 64;
    // ---- stage K via global_load_lds: chunk c covers LDS [c*1024, +1024) bytes
#pragma unroll
    for (int i = 0; i < 2; ++i) {
      const int c = i * 4 + w;
      const int ks = c >> 2;
      const int kvl = (c & 3) * 16 + (lane >> 2);
      const int dl = (lane & 3) * 8;
      gld_lds16(Kb + (size_t)(kv0 + kvl) * Dd + ks * 32 + dl,
                (char*)Ks + c * 1024);
    }
    // ---- stage V transposed (register transpose, 2 kv rows per thread)
    {
      const int p = tid >> 3;            // kv pair 0..31
      const int d0 = (tid & 7) * 8;
      const int kv = 2 * p;
      const int kh = kv >> 5, kvlo = kv & 31;
      bf16x8 v0 = *(const bf16x8*)&Vb[(size_t)(kv0 + kv) * Dd + d0];
      bf16x8 v1 = *(const bf16x8*)&Vb[(size_t)(kv0 + kv + 1) * Dd + d0];
#pragma unroll
      for (int j = 0; j < 8; ++j) {
        bf16* dst = &Vs[kh][d0 + j][kvlo];
        dst[0] = v0[j];
        dst[1] = v1[j];
      }
    }
    __syncthreads();

    // ---- QK^T : S[q, kv]  (A=Q frag, B=K frag)
    f32x4 sf[4] = {};
#pragma unroll
    for (int n = 0; n < 4; ++n) {
#pragma unroll
      for (int ks = 0; ks < 2; ++ks) {
        bf16x8 kf = *(const bf16x8*)&Ks[ks][n * 16 + (lane & 15)][(lane >> 4) * 8];
        sf[n] = MFMA(qf[ks], kf, sf[n]);
      }
    }

    // ---- online softmax
    const int qrb = q0 + w * 16 + (lane >> 4) * 4;   // + r
    float mchunk[4];
#pragma unroll
    for (int r = 0; r < 4; ++r) mchunk[r] = -INFINITY;
#pragma unroll
    for (int n = 0; n < 4; ++n) {
      const int kvcol = kv0 + n * 16 + (lane & 15);
#pragma unroll
      for (int r = 0; r < 4; ++r) {
        float sv = sf[n][r] * 0.125f;
        if (kvcol > qrb + r) sv = -INFINITY;         // causal
        sf[n][r] = sv;
        mchunk[r] = fmaxf(mchunk[r], sv);
      }
    }
#pragma unroll
    for (int off = 1; off < 16; off <<= 1)
#pragma unroll
      for (int r = 0; r < 4; ++r)
        mchunk[r] = fmaxf(mchunk[r], __shfl_xor(mchunk[r], off, 64));

    float alpha[4], rsum[4];
#pragma unroll
    for (int r = 0; r < 4; ++r) {
      const float mn = fmaxf(m_run[r], mchunk[r]);
      alpha[r] = __expf(m_run[r] - mn);   // first chunk: exp(-inf)=0
      m_run[r] = mn;
      rsum[r] = 0.f;
    }
#pragma unroll
    for (int n = 0; n < 4; ++n)
#pragma unroll
      for (int r = 0; r < 4; ++r) {
        const float p = __expf(sf[n][r] - m_run[r]);
        rsum[r] += p;
        Ps[w][(lane >> 4) * 4 + r][n * 16 + (lane & 15)] = (bf16)p;
      }
#pragma unroll
    for (int off = 1; off < 16; off <<= 1)
#pragma unroll
      for (int r = 0; r < 4; ++r)
        rsum[r] += __shfl_xor(rsum[r], off, 64);
#pragma unroll
    for (int r = 0; r < 4; ++r)
      l_run[r] = l_run[r] * alpha[r] + rsum[r];
#pragma unroll
    for (int n = 0; n < 4; ++n)
#pragma unroll
      for (int r = 0; r < 4; ++r)
        of[n][r] *= alpha[r];

    // ---- PV : O[q, d] += P[q, kv] * V[kv, d]
#pragma unroll
    for (int ks = 0; ks < 2; ++ks) {
      bf16x8 pfr = *(const bf16x8*)&Ps[w][lane & 15][ks * 32 + (lane >> 4) * 8];
#pragma unroll
      for (int n = 0; n < 4; ++n) {
        bf16x8 vf = *(const bf16x8*)&Vs[ks][n * 16 + (lane & 15)][(lane >> 4) * 8];
        of[n] = MFMA(pfr, vf, of[n]);
      }
    }
    __syncthreads();   // before restaging K/V
  }

  // ---- epilogue: O / l, write bf16 to X [B,S,D]
  bf16* Xb = X + (size_t)b * Ss * Dd + h * DKk;
#pragma unroll
  for (int n = 0; n < 4; ++n)
#pragma unroll
    for (int r = 0; r < 4; ++r) {
      const int q = q0 + w * 16 + (lane >> 4) * 4 + r;
      const float v = of[n][r] / l_run[r];
      Xb[(size_t)q * Dd + n * 16 + (lane & 15)] = (bf16)v;
    }
}

// ---------------------------------------------------------------- launch
extern "C" void kernel_launch(void* const* d_in, const int* in_sizes, int n_in,
                              void* d_out, int out_size, void* d_ws, size_t ws_size,
                              hipStream_t stream) {
  const float* query = (const float*)d_in[0];
  const float* key   = (const float*)d_in[1];
  const float* value = (const float*)d_in[2];
  // d_in[3] = mask: tril by construction; causal handled analytically
  const float* Wq = (const float*)d_in[4];
  const float* bq = (const float*)d_in[5];
  const float* Wk = (const float*)d_in[6];
  const float* bk = (const float*)d_in[7];
  const float* Wv = (const float*)d_in[8];
  const float* bv = (const float*)d_in[9];
  const float* Wo = (const float*)d_in[10];
  const float* bo = (const float*)d_in[11];

  char* ws = (char*)d_ws;
  bf16* qb  = (bf16*)(ws + (0ull  << 20));
  bf16* kb  = (bf16*)(ws + (8ull  << 20));
  bf16* vb  = (bf16*)(ws + (16ull << 20));
  bf16* wqb = (bf16*)(ws + (24ull << 20));
  bf16* wkb = (bf16*)(ws + (26ull << 20));
  bf16* wvb = (bf16*)(ws + (28ull << 20));
  bf16* wob = (bf16*)(ws + (30ull << 20));
  bf16* Qp  = (bf16*)(ws + (32ull << 20));
  bf16* Kp  = (bf16*)(ws + (40ull << 20));
  bf16* Vp  = (bf16*)(ws + (48ull << 20));
  bf16* Xa  = (bf16*)(ws + (56ull << 20));

  const int NT4 = (Bb * Ss * Dd) / 4;   // 1048576
  const int NW4 = (Dd * Dd) / 4;        // 262144

  cvt_f32_bf16<<<NT4 / 256, 256, 0, stream>>>(query, qb, NT4);
  cvt_f32_bf16<<<NT4 / 256, 256, 0, stream>>>(key,   kb, NT4);
  cvt_f32_bf16<<<NT4 / 256, 256, 0, stream>>>(value, vb, NT4);
  cvt_f32_bf16<<<NW4 / 256, 256, 0, stream>>>(Wq, wqb, NW4);
  cvt_f32_bf16<<<NW4 / 256, 256, 0, stream>>>(Wk, wkb, NW4);
  cvt_f32_bf16<<<NW4 / 256, 256, 0, stream>>>(Wv, wvb, NW4);
  cvt_f32_bf16<<<NW4 / 256, 256, 0, stream>>>(Wo, wob, NW4);

  dim3 gg(8, 32);   // N/128, M/128
  gemm_bt<false><<<gg, 256, 0, stream>>>(qb, wqb, bq, Qp, nullptr);
  gemm_bt<false><<<gg, 256, 0, stream>>>(kb, wkb, bk, Kp, nullptr);
  gemm_bt<false><<<gg, 256, 0, stream>>>(vb, wvb, bv, Vp, nullptr);

  attn_fwd<<<dim3(32, 32), 256, 0, stream>>>(Qp, Kp, Vp, Xa);

  gemm_bt<true><<<gg, 256, 0, stream>>>(Xa, wob, bo, nullptr, (float*)d_out);
}

// Round 9
// 384.559 us; speedup vs baseline: 1.0013x; 1.0013x over previous
//

#include <hip/hip_runtime.h>
#include <hip/hip_bf16.h>

// Problem constants
#define Bb 2
#define Ss 2048
#define Dd 1024
#define Hh 16
#define DKk 64
#define Mm (Bb*Ss)          // 4096 rows in all GEMMs

typedef __bf16 bf16;
typedef __attribute__((ext_vector_type(8))) __bf16 bf16x8;
typedef __attribute__((ext_vector_type(4))) __bf16 bf16x4;
typedef __attribute__((ext_vector_type(4))) float  f32x4;

#define MFMA(Af, Bf, Cf) __builtin_amdgcn_mfma_f32_16x16x32_bf16(Af, Bf, Cf, 0, 0, 0)

__device__ __forceinline__ void gld_lds16(const void* g, void* l) {
  __builtin_amdgcn_global_load_lds(
      (const __attribute__((address_space(1))) void*)g,
      (__attribute__((address_space(3))) void*)l, 16, 0, 0);
}

// ---------------------------------------------------------------- convert
__global__ __launch_bounds__(256) void cvt_f32_bf16(
    const float* __restrict__ s, bf16* __restrict__ d, int n4) {
  int i = blockIdx.x * 256 + threadIdx.x;
  if (i >= n4) return;
  float4 v = reinterpret_cast<const float4*>(s)[i];
  bf16x4 o;
  o[0] = (bf16)v.x; o[1] = (bf16)v.y; o[2] = (bf16)v.z; o[3] = (bf16)v.w;
  reinterpret_cast<bf16x4*>(d)[i] = o;
}

// ---------------------------------------------------------------- GEMM (B^T)
// C[i,j] = sum_k A[i,k] * W[j,k] + bias[j]      M=4096, N=1024, K=1024
// 128x128 tile, BK=32, 256 threads = 4 waves (2x2), global_load_lds staging.
template <bool F32OUT>
__global__ __launch_bounds__(256) void gemm_bt(
    const bf16* __restrict__ A, const bf16* __restrict__ W,
    const float* __restrict__ bias, bf16* __restrict__ out_bf,
    float* __restrict__ out_f32) {
  constexpr int N = 1024, K = 1024;
  __shared__ bf16 As[128 * 32];
  __shared__ bf16 Bs[128 * 32];
  const int tid = threadIdx.x;
  const int w = tid >> 6, lane = tid & 63;
  const int wr = w >> 1, wc = w & 1;
  const int row0 = blockIdx.y * 128, col0 = blockIdx.x * 128;
  const bf16* Ab = A + (size_t)row0 * K;
  const bf16* Wb = W + (size_t)col0 * K;

  f32x4 acc[4][4] = {};

  for (int kt = 0; kt < K / 32; ++kt) {
    const int k0 = kt * 32;
    // stage A and B tiles: 8KB each, 8 wave-instrs each (2 per wave)
#pragma unroll
    for (int i = 0; i < 2; ++i) {
      const int c = i * 4 + w;                 // 1KB chunk id
      const int r = c * 16 + (lane >> 2);      // tile row
      const int ce = (lane & 3) * 8;           // k element offset within BK
      gld_lds16(Ab + (size_t)r * K + k0 + ce, (char*)As + c * 1024);
      gld_lds16(Wb + (size_t)r * K + k0 + ce, (char*)Bs + c * 1024);
    }
    __syncthreads();

    bf16x8 af[4], bfr[4];
#pragma unroll
    for (int m = 0; m < 4; ++m) {
      const int r = wr * 64 + m * 16 + (lane & 15);
      af[m] = *(const bf16x8*)&As[r * 32 + (lane >> 4) * 8];
    }
#pragma unroll
    for (int n = 0; n < 4; ++n) {
      const int r = wc * 64 + n * 16 + (lane & 15);
      bfr[n] = *(const bf16x8*)&Bs[r * 32 + (lane >> 4) * 8];
    }
#pragma unroll
    for (int m = 0; m < 4; ++m)
#pragma unroll
      for (int n = 0; n < 4; ++n)
        acc[m][n] = MFMA(af[m], bfr[n], acc[m][n]);
    __syncthreads();
  }

  // epilogue: C/D layout col=lane&15, row=(lane>>4)*4+reg
  const int g = lane >> 4, c15 = lane & 15;
#pragma unroll
  for (int n = 0; n < 4; ++n) {
    const int col = col0 + wc * 64 + n * 16 + c15;
    const float bv = bias[col];
#pragma unroll
    for (int m = 0; m < 4; ++m) {
      const int rbase = row0 + wr * 64 + m * 16 + g * 4;
#pragma unroll
      for (int r = 0; r < 4; ++r) {
        const float v = acc[m][n][r] + bv;
        if (F32OUT) out_f32[(size_t)(rbase + r) * N + col] = v;
        else        out_bf [(size_t)(rbase + r) * N + col] = (bf16)v;
      }
    }
  }
}

// ---------------------------------------------------------------- attention
// One block = 64 q-rows of one (b,h). 4 waves, 16 q-rows each.
// K staged [2(ks=d-half)][64 kv][32 d]  (linear for global_load_lds, conflict-free reads)
// V staged transposed [2(kh=kv-half)][64 d][32 kv]
__global__ __launch_bounds__(256) void attn_fwd(
    const bf16* __restrict__ Q, const bf16* __restrict__ K,
    const bf16* __restrict__ V, bf16* __restrict__ X) {
  __shared__ bf16 Ks[2][64][32];
  __shared__ bf16 Vs[2][64][32];
  __shared__ bf16 Ps[4][16][64];

  const int tid = threadIdx.x;
  const int w = tid >> 6, lane = tid & 63;
  const int bh = blockIdx.y, b = bh >> 4, h = bh & 15;
  const int qt = blockIdx.x, q0 = qt * 64;

  const bf16* Qb = Q + (size_t)b * Ss * Dd + h * DKk;
  const bf16* Kb = K + (size_t)b * Ss * Dd + h * DKk;
  const bf16* Vb = V + (size_t)b * Ss * Dd + h * DKk;

  // Q fragments in registers: rows q0+w*16+(lane&15), k=d contiguous
  bf16x8 qf[2];
  {
    const int qr = q0 + w * 16 + (lane & 15);
    const int d0 = (lane >> 4) * 8;
    qf[0] = *(const bf16x8*)&Qb[(size_t)qr * Dd + d0];
    qf[1] = *(const bf16x8*)&Qb[(size_t)qr * Dd + d0 + 32];
  }

  f32x4 of[4] = {};
  float m_run[4], l_run[4];
#pragma unroll
  for (int r = 0; r < 4; ++r) { m_run[r] = -INFINITY; l_run[r] = 0.f; }

  const int nchunks = qt + 1;
  for (int ct = 0; ct < nchunks; ++ct) {
    const int kv0 = ct * 64;
    // ---- stage K via global_load_lds: chunk c covers LDS [c*1024, +1024) bytes
#pragma unroll
    for (int i = 0; i < 2; ++i) {
      const int c = i * 4 + w;
      const int ks = c >> 2;
      const int kvl = (c & 3) * 16 + (lane >> 2);
      const int dl = (lane & 3) * 8;
      gld_lds16(Kb + (size_t)(kv0 + kvl) * Dd + ks * 32 + dl,
                (char*)Ks + c * 1024);
    }
    // ---- stage V transposed (register transpose, 2 kv rows per thread)
    {
      const int p = tid >> 3;            // kv pair 0..31
      const int d0 = (tid & 7) * 8;
      const int kv = 2 * p;
      const int kh = kv >> 5, kvlo = kv & 31;
      bf16x8 v0 = *(const bf16x8*)&Vb[(size_t)(kv0 + kv) * Dd + d0];
      bf16x8 v1 = *(const bf16x8*)&Vb[(size_t)(kv0 + kv + 1) * Dd + d0];
#pragma unroll
      for (int j = 0; j < 8; ++j) {
        bf16* dst = &Vs[kh][d0 + j][kvlo];
        dst[0] = v0[j];
        dst[1] = v1[j];
      }
    }
    __syncthreads();

    // ---- QK^T : S[q, kv]  (A=Q frag, B=K frag)
    f32x4 sf[4] = {};
#pragma unroll
    for (int n = 0; n < 4; ++n) {
#pragma unroll
      for (int ks = 0; ks < 2; ++ks) {
        bf16x8 kf = *(const bf16x8*)&Ks[ks][n * 16 + (lane & 15)][(lane >> 4) * 8];
        sf[n] = MFMA(qf[ks], kf, sf[n]);
      }
    }

    // ---- online softmax
    const int qrb = q0 + w * 16 + (lane >> 4) * 4;   // + r
    float mchunk[4];
#pragma unroll
    for (int r = 0; r < 4; ++r) mchunk[r] = -INFINITY;
#pragma unroll
    for (int n = 0; n < 4; ++n) {
      const int kvcol = kv0 + n * 16 + (lane & 15);
#pragma unroll
      for (int r = 0; r < 4; ++r) {
        float sv = sf[n][r] * 0.125f;
        if (kvcol > qrb + r) sv = -INFINITY;         // causal
        sf[n][r] = sv;
        mchunk[r] = fmaxf(mchunk[r], sv);
      }
    }
#pragma unroll
    for (int off = 1; off < 16; off <<= 1)
#pragma unroll
      for (int r = 0; r < 4; ++r)
        mchunk[r] = fmaxf(mchunk[r], __shfl_xor(mchunk[r], off, 64));

    float alpha[4], rsum[4];
#pragma unroll
    for (int r = 0; r < 4; ++r) {
      const float mn = fmaxf(m_run[r], mchunk[r]);
      alpha[r] = __expf(m_run[r] - mn);   // first chunk: exp(-inf)=0
      m_run[r] = mn;
      rsum[r] = 0.f;
    }
#pragma unroll
    for (int n = 0; n < 4; ++n)
#pragma unroll
      for (int r = 0; r < 4; ++r) {
        const float p = __expf(sf[n][r] - m_run[r]);
        rsum[r] += p;
        Ps[w][(lane >> 4) * 4 + r][n * 16 + (lane & 15)] = (bf16)p;
      }
#pragma unroll
    for (int off = 1; off < 16; off <<= 1)
#pragma unroll
      for (int r = 0; r < 4; ++r)
        rsum[r] += __shfl_xor(rsum[r], off, 64);
#pragma unroll
    for (int r = 0; r < 4; ++r)
      l_run[r] = l_run[r] * alpha[r] + rsum[r];
#pragma unroll
    for (int n = 0; n < 4; ++n)
#pragma unroll
      for (int r = 0; r < 4; ++r)
        of[n][r] *= alpha[r];

    // ---- PV : O[q, d] += P[q, kv] * V[kv, d]
#pragma unroll
    for (int ks = 0; ks < 2; ++ks) {
      bf16x8 pfr = *(const bf16x8*)&Ps[w][lane & 15][ks * 32 + (lane >> 4) * 8];
#pragma unroll
      for (int n = 0; n < 4; ++n) {
        bf16x8 vf = *(const bf16x8*)&Vs[ks][n * 16 + (lane & 15)][(lane >> 4) * 8];
        of[n] = MFMA(pfr, vf, of[n]);
      }
    }
    __syncthreads();   // before restaging K/V
  }

  // ---- epilogue: O / l, write bf16 to X [B,S,D]
  bf16* Xb = X + (size_t)b * Ss * Dd + h * DKk;
#pragma unroll
  for (int n = 0; n < 4; ++n)
#pragma unroll
    for (int r = 0; r < 4; ++r) {
      const int q = q0 + w * 16 + (lane >> 4) * 4 + r;
      const float v = of[n][r] / l_run[r];
      Xb[(size_t)q * Dd + n * 16 + (lane & 15)] = (bf16)v;
    }
}

// ---------------------------------------------------------------- launch
extern "C" void kernel_launch(void* const* d_in, const int* in_sizes, int n_in,
                              void* d_out, int out_size, void* d_ws, size_t ws_size,
                              hipStream_t stream) {
  const float* query = (const float*)d_in[0];
  const float* key   = (const float*)d_in[1];
  const float* value = (const float*)d_in[2];
  // d_in[3] = mask: tril by construction; causal handled analytically
  const float* Wq = (const float*)d_in[4];
  const float* bq = (const float*)d_in[5];
  const float* Wk = (const float*)d_in[6];
  const float* bk = (const float*)d_in[7];
  const float* Wv = (const float*)d_in[8];
  const float* bv = (const float*)d_in[9];
  const float* Wo = (const float*)d_in[10];
  const float* bo = (const float*)d_in[11];

  char* ws = (char*)d_ws;
  bf16* qb  = (bf16*)(ws + (0ull  << 20));
  bf16* kb  = (bf16*)(ws + (8ull  << 20));
  bf16* vb  = (bf16*)(ws + (16ull << 20));
  bf16* wqb = (bf16*)(ws + (24ull << 20));
  bf16* wkb = (bf16*)(ws + (26ull << 20));
  bf16* wvb = (bf16*)(ws + (28ull << 20));
  bf16* wob = (bf16*)(ws + (30ull << 20));
  bf16* Qp  = (bf16*)(ws + (32ull << 20));
  bf16* Kp  = (bf16*)(ws + (40ull << 20));
  bf16* Vp  = (bf16*)(ws + (48ull << 20));
  bf16* Xa  = (bf16*)(ws + (56ull << 20));

  const int NT4 = (Bb * Ss * Dd) / 4;   // 1048576
  const int NW4 = (Dd * Dd) / 4;        // 262144

  cvt_f32_bf16<<<NT4 / 256, 256, 0, stream>>>(query, qb, NT4);
  cvt_f32_bf16<<<NT4 / 256, 256, 0, stream>>>(key,   kb, NT4);
  cvt_f32_bf16<<<NT4 / 256, 256, 0, stream>>>(value, vb, NT4);
  cvt_f32_bf16<<<NW4 / 256, 256, 0, stream>>>(Wq, wqb, NW4);
  cvt_f32_bf16<<<NW4 / 256, 256, 0, stream>>>(Wk, wkb, NW4);
  cvt_f32_bf16<<<NW4 / 256, 256, 0, stream>>>(Wv, wvb, NW4);
  cvt_f32_bf16<<<NW4 / 256, 256, 0, stream>>>(Wo, wob, NW4);

  dim3 gg(8, 32);   // N/128, M/128
  gemm_bt<false><<<gg, 256, 0, stream>>>(qb, wqb, bq, Qp, nullptr);
  gemm_bt<false><<<gg, 256, 0, stream>>>(kb, wkb, bk, Kp, nullptr);
  gemm_bt<false><<<gg, 256, 0, stream>>>(vb, wvb, bv, Vp, nullptr);

  attn_fwd<<<dim3(32, 32), 256, 0, stream>>>(Qp, Kp, Vp, Xa);

  gemm_bt<true><<<gg, 256, 0, stream>>>(Xa, wob, bo, nullptr, (float*)d_out);
}

// Round 10
// 334.094 us; speedup vs baseline: 1.1526x; 1.1511x over previous
//

#include <hip/hip_runtime.h>
#include <hip/hip_bf16.h>

// Problem constants
#define Bb 2
#define Ss 2048
#define Dd 1024
#define Hh 16
#define DKk 64
#define Mm (Bb*Ss)          // 4096 rows in all GEMMs

typedef __bf16 bf16;
typedef __attribute__((ext_vector_type(8))) __bf16 bf16x8;
typedef __attribute__((ext_vector_type(4))) __bf16 bf16x4;
typedef __attribute__((ext_vector_type(4))) float  f32x4;

#define MFMA(Af, Bf, Cf) __builtin_amdgcn_mfma_f32_16x16x32_bf16(Af, Bf, Cf, 0, 0, 0)

__device__ __forceinline__ void gld_lds16(const void* g, void* l) {
  __builtin_amdgcn_global_load_lds(
      (const __attribute__((address_space(1))) void*)g,
      (__attribute__((address_space(3))) void*)l, 16, 0, 0);
}

// ---------------------------------------------------------------- convert
__global__ __launch_bounds__(256) void cvt_f32_bf16(
    const float* __restrict__ s, bf16* __restrict__ d, int n4) {
  int i = blockIdx.x * 256 + threadIdx.x;
  if (i >= n4) return;
  float4 v = reinterpret_cast<const float4*>(s)[i];
  bf16x4 o;
  o[0] = (bf16)v.x; o[1] = (bf16)v.y; o[2] = (bf16)v.z; o[3] = (bf16)v.w;
  reinterpret_cast<bf16x4*>(d)[i] = o;
}

// ---------------------------------------------------------------- GEMM (B^T)
// C[i,j] = sum_k A[i,k] * W[j,k] + bias[j]      M=4096, N=1024, K=1024
// 128x128 tile, BK=32, 256 threads = 4 waves (2x2), global_load_lds staging.
// (VERBATIM from passing R9.)
template <bool F32OUT>
__global__ __launch_bounds__(256) void gemm_bt(
    const bf16* __restrict__ A, const bf16* __restrict__ W,
    const float* __restrict__ bias, bf16* __restrict__ out_bf,
    float* __restrict__ out_f32) {
  constexpr int N = 1024, K = 1024;
  __shared__ bf16 As[128 * 32];
  __shared__ bf16 Bs[128 * 32];
  const int tid = threadIdx.x;
  const int w = tid >> 6, lane = tid & 63;
  const int wr = w >> 1, wc = w & 1;
  const int row0 = blockIdx.y * 128, col0 = blockIdx.x * 128;
  const bf16* Ab = A + (size_t)row0 * K;
  const bf16* Wb = W + (size_t)col0 * K;

  f32x4 acc[4][4] = {};

  for (int kt = 0; kt < K / 32; ++kt) {
    const int k0 = kt * 32;
#pragma unroll
    for (int i = 0; i < 2; ++i) {
      const int c = i * 4 + w;                 // 1KB chunk id
      const int r = c * 16 + (lane >> 2);      // tile row
      const int ce = (lane & 3) * 8;           // k element offset within BK
      gld_lds16(Ab + (size_t)r * K + k0 + ce, (char*)As + c * 1024);
      gld_lds16(Wb + (size_t)r * K + k0 + ce, (char*)Bs + c * 1024);
    }
    __syncthreads();

    bf16x8 af[4], bfr[4];
#pragma unroll
    for (int m = 0; m < 4; ++m) {
      const int r = wr * 64 + m * 16 + (lane & 15);
      af[m] = *(const bf16x8*)&As[r * 32 + (lane >> 4) * 8];
    }
#pragma unroll
    for (int n = 0; n < 4; ++n) {
      const int r = wc * 64 + n * 16 + (lane & 15);
      bfr[n] = *(const bf16x8*)&Bs[r * 32 + (lane >> 4) * 8];
    }
#pragma unroll
    for (int m = 0; m < 4; ++m)
#pragma unroll
      for (int n = 0; n < 4; ++n)
        acc[m][n] = MFMA(af[m], bfr[n], acc[m][n]);
    __syncthreads();
  }

  // epilogue: C/D layout col=lane&15, row=(lane>>4)*4+reg
  const int g = lane >> 4, c15 = lane & 15;
#pragma unroll
  for (int n = 0; n < 4; ++n) {
    const int col = col0 + wc * 64 + n * 16 + c15;
    const float bv = bias[col];
#pragma unroll
    for (int m = 0; m < 4; ++m) {
      const int rbase = row0 + wr * 64 + m * 16 + g * 4;
#pragma unroll
      for (int r = 0; r < 4; ++r) {
        const float v = acc[m][n][r] + bv;
        if (F32OUT) out_f32[(size_t)(rbase + r) * N + col] = v;
        else        out_bf [(size_t)(rbase + r) * N + col] = (bf16)v;
      }
    }
  }
}

// ---------------------------------------------------------------- attention
// R9 core, verbatim, with ONE delta: paired q-tiles.
// One block = q-tiles (31-z) then (z) of one (b,h): exactly 33 chunk-units
// per block, 512 balanced blocks (load balance; fixes straggler serialization).
__global__ __launch_bounds__(256) void attn_fwd(
    const bf16* __restrict__ Q, const bf16* __restrict__ K,
    const bf16* __restrict__ V, bf16* __restrict__ X) {
  __shared__ bf16 Ks[2][64][32];
  __shared__ bf16 Vs[2][64][32];
  __shared__ bf16 Ps[4][16][64];

  const int tid = threadIdx.x;
  const int w = tid >> 6, lane = tid & 63;
  const int z = blockIdx.x & 15, bh = blockIdx.x >> 4;
  const int b = bh >> 4, h = bh & 15;

  const bf16* Qb = Q + (size_t)b * Ss * Dd + h * DKk;
  const bf16* Kb = K + (size_t)b * Ss * Dd + h * DKk;
  const bf16* Vb = V + (size_t)b * Ss * Dd + h * DKk;
  bf16* Xb = X + (size_t)b * Ss * Dd + h * DKk;

  for (int pass = 0; pass < 2; ++pass) {
    const int qt = pass ? z : 31 - z;
    const int q0 = qt * 64;

    // Q fragments in registers: rows q0+w*16+(lane&15), k=d contiguous
    bf16x8 qf[2];
    {
      const int qr = q0 + w * 16 + (lane & 15);
      const int d0 = (lane >> 4) * 8;
      qf[0] = *(const bf16x8*)&Qb[(size_t)qr * Dd + d0];
      qf[1] = *(const bf16x8*)&Qb[(size_t)qr * Dd + d0 + 32];
    }

    f32x4 of[4] = {};
    float m_run[4], l_run[4];
#pragma unroll
    for (int r = 0; r < 4; ++r) { m_run[r] = -INFINITY; l_run[r] = 0.f; }

    const int nchunks = qt + 1;
    for (int ct = 0; ct < nchunks; ++ct) {
      const int kv0 = ct * 64;
      // ---- stage K via global_load_lds: chunk c covers LDS [c*1024, +1024)
#pragma unroll
      for (int i = 0; i < 2; ++i) {
        const int c = i * 4 + w;
        const int ks = c >> 2;
        const int kvl = (c & 3) * 16 + (lane >> 2);
        const int dl = (lane & 3) * 8;
        gld_lds16(Kb + (size_t)(kv0 + kvl) * Dd + ks * 32 + dl,
                  (char*)Ks + c * 1024);
      }
      // ---- stage V transposed (register transpose, 2 kv rows per thread)
      {
        const int p = tid >> 3;            // kv pair 0..31
        const int d0 = (tid & 7) * 8;
        const int kv = 2 * p;
        const int kh = kv >> 5, kvlo = kv & 31;
        bf16x8 v0 = *(const bf16x8*)&Vb[(size_t)(kv0 + kv) * Dd + d0];
        bf16x8 v1 = *(const bf16x8*)&Vb[(size_t)(kv0 + kv + 1) * Dd + d0];
#pragma unroll
        for (int j = 0; j < 8; ++j) {
          bf16* dst = &Vs[kh][d0 + j][kvlo];
          dst[0] = v0[j];
          dst[1] = v1[j];
        }
      }
      __syncthreads();

      // ---- QK^T : S[q, kv]  (A=Q frag, B=K frag)
      f32x4 sf[4] = {};
#pragma unroll
      for (int n = 0; n < 4; ++n) {
#pragma unroll
        for (int ks = 0; ks < 2; ++ks) {
          bf16x8 kf = *(const bf16x8*)&Ks[ks][n * 16 + (lane & 15)][(lane >> 4) * 8];
          sf[n] = MFMA(qf[ks], kf, sf[n]);
        }
      }

      // ---- online softmax
      const int qrb = q0 + w * 16 + (lane >> 4) * 4;   // + r
      float mchunk[4];
#pragma unroll
      for (int r = 0; r < 4; ++r) mchunk[r] = -INFINITY;
#pragma unroll
      for (int n = 0; n < 4; ++n) {
        const int kvcol = kv0 + n * 16 + (lane & 15);
#pragma unroll
        for (int r = 0; r < 4; ++r) {
          float sv = sf[n][r] * 0.125f;
          if (kvcol > qrb + r) sv = -INFINITY;         // causal
          sf[n][r] = sv;
          mchunk[r] = fmaxf(mchunk[r], sv);
        }
      }
#pragma unroll
      for (int off = 1; off < 16; off <<= 1)
#pragma unroll
        for (int r = 0; r < 4; ++r)
          mchunk[r] = fmaxf(mchunk[r], __shfl_xor(mchunk[r], off, 64));

      float alpha[4], rsum[4];
#pragma unroll
      for (int r = 0; r < 4; ++r) {
        const float mn = fmaxf(m_run[r], mchunk[r]);
        alpha[r] = __expf(m_run[r] - mn);   // first chunk: exp(-inf)=0
        m_run[r] = mn;
        rsum[r] = 0.f;
      }
#pragma unroll
      for (int n = 0; n < 4; ++n)
#pragma unroll
        for (int r = 0; r < 4; ++r) {
          const float p = __expf(sf[n][r] - m_run[r]);
          rsum[r] += p;
          Ps[w][(lane >> 4) * 4 + r][n * 16 + (lane & 15)] = (bf16)p;
        }
#pragma unroll
      for (int off = 1; off < 16; off <<= 1)
#pragma unroll
        for (int r = 0; r < 4; ++r)
          rsum[r] += __shfl_xor(rsum[r], off, 64);
#pragma unroll
      for (int r = 0; r < 4; ++r)
        l_run[r] = l_run[r] * alpha[r] + rsum[r];
#pragma unroll
      for (int n = 0; n < 4; ++n)
#pragma unroll
        for (int r = 0; r < 4; ++r)
          of[n][r] *= alpha[r];

      // ---- PV : O[q, d] += P[q, kv] * V[kv, d]
#pragma unroll
      for (int ks = 0; ks < 2; ++ks) {
        bf16x8 pfr = *(const bf16x8*)&Ps[w][lane & 15][ks * 32 + (lane >> 4) * 8];
#pragma unroll
        for (int n = 0; n < 4; ++n) {
          bf16x8 vf = *(const bf16x8*)&Vs[ks][n * 16 + (lane & 15)][(lane >> 4) * 8];
          of[n] = MFMA(pfr, vf, of[n]);
        }
      }
      __syncthreads();   // before restaging K/V
    }

    // ---- epilogue: O / l, write bf16 to X [B,S,D]
#pragma unroll
    for (int n = 0; n < 4; ++n)
#pragma unroll
      for (int r = 0; r < 4; ++r) {
        const int q = q0 + w * 16 + (lane >> 4) * 4 + r;
        const float v = of[n][r] / l_run[r];
        Xb[(size_t)q * Dd + n * 16 + (lane & 15)] = (bf16)v;
      }
  }
}

// ---------------------------------------------------------------- launch
extern "C" void kernel_launch(void* const* d_in, const int* in_sizes, int n_in,
                              void* d_out, int out_size, void* d_ws, size_t ws_size,
                              hipStream_t stream) {
  const float* query = (const float*)d_in[0];
  const float* key   = (const float*)d_in[1];
  const float* value = (const float*)d_in[2];
  // d_in[3] = mask: tril by construction; causal handled analytically
  const float* Wq = (const float*)d_in[4];
  const float* bq = (const float*)d_in[5];
  const float* Wk = (const float*)d_in[6];
  const float* bk = (const float*)d_in[7];
  const float* Wv = (const float*)d_in[8];
  const float* bv = (const float*)d_in[9];
  const float* Wo = (const float*)d_in[10];
  const float* bo = (const float*)d_in[11];

  char* ws = (char*)d_ws;
  bf16* qb  = (bf16*)(ws + (0ull  << 20));
  bf16* kb  = (bf16*)(ws + (8ull  << 20));
  bf16* vb  = (bf16*)(ws + (16ull << 20));
  bf16* wqb = (bf16*)(ws + (24ull << 20));
  bf16* wkb = (bf16*)(ws + (26ull << 20));
  bf16* wvb = (bf16*)(ws + (28ull << 20));
  bf16* wob = (bf16*)(ws + (30ull << 20));
  bf16* Qp  = (bf16*)(ws + (32ull << 20));
  bf16* Kp  = (bf16*)(ws + (40ull << 20));
  bf16* Vp  = (bf16*)(ws + (48ull << 20));
  bf16* Xa  = (bf16*)(ws + (56ull << 20));

  const int NT4 = (Bb * Ss * Dd) / 4;   // 1048576
  const int NW4 = (Dd * Dd) / 4;        // 262144

  cvt_f32_bf16<<<NT4 / 256, 256, 0, stream>>>(query, qb, NT4);
  cvt_f32_bf16<<<NT4 / 256, 256, 0, stream>>>(key,   kb, NT4);
  cvt_f32_bf16<<<NT4 / 256, 256, 0, stream>>>(value, vb, NT4);
  cvt_f32_bf16<<<NW4 / 256, 256, 0, stream>>>(Wq, wqb, NW4);
  cvt_f32_bf16<<<NW4 / 256, 256, 0, stream>>>(Wk, wkb, NW4);
  cvt_f32_bf16<<<NW4 / 256, 256, 0, stream>>>(Wv, wvb, NW4);
  cvt_f32_bf16<<<NW4 / 256, 256, 0, stream>>>(Wo, wob, NW4);

  dim3 gg(8, 32);   // N/128, M/128
  gemm_bt<false><<<gg, 256, 0, stream>>>(qb, wqb, bq, Qp, nullptr);
  gemm_bt<false><<<gg, 256, 0, stream>>>(kb, wkb, bk, Kp, nullptr);
  gemm_bt<false><<<gg, 256, 0, stream>>>(vb, wvb, bv, Vp, nullptr);

  attn_fwd<<<512, 256, 0, stream>>>(Qp, Kp, Vp, Xa);

  gemm_bt<true><<<gg, 256, 0, stream>>>(Xa, wob, bo, nullptr, (float*)d_out);
}

// Round 12
// 291.575 us; speedup vs baseline: 1.3206x; 1.1458x over previous
//
#include <hip/hip_runtime.h>
#include <hip/hip_bf16.h>

// Problem constants
#define Bb 2
#define Ss 2048
#define Dd 1024
#define Hh 16
#define DKk 64

typedef __bf16 bf16;
typedef __attribute__((ext_vector_type(8))) __bf16 bf16x8;
typedef __attribute__((ext_vector_type(4))) __bf16 bf16x4;
typedef __attribute__((ext_vector_type(4))) float  f32x4;

#define MFMA(Af, Bf, Cf) __builtin_amdgcn_mfma_f32_16x16x32_bf16(Af, Bf, Cf, 0, 0, 0)

__device__ __forceinline__ void gld_lds16(const void* g, void* l) {
  __builtin_amdgcn_global_load_lds(
      (const __attribute__((address_space(1))) void*)g,
      (__attribute__((address_space(3))) void*)l, 16, 0, 0);
}

// ---------------------------------------------------------------- prep
// All fp32->bf16 conversions in ONE kernel. Packs Wq,Wk,Wv into wqkv
// [3072 rows (=output col)][1024]. NO scale folding (attn applies 0.125).
__global__ __launch_bounds__(256) void prep(
    const float* __restrict__ q, const float* __restrict__ k, const float* __restrict__ v,
    const float* __restrict__ Wq, const float* __restrict__ Wk, const float* __restrict__ Wv,
    const float* __restrict__ Wo,
    bf16* __restrict__ qb, bf16* __restrict__ kb, bf16* __restrict__ vb,
    bf16* __restrict__ wqkv, bf16* __restrict__ wob) {
  const int bid = blockIdx.x;
  const float* src; bf16* dst; int idx;
  if (bid < 4096)       { src = q;  dst = qb; idx = bid; }
  else if (bid < 8192)  { src = k;  dst = kb; idx = bid - 4096; }
  else if (bid < 12288) { src = v;  dst = vb; idx = bid - 8192; }
  else if (bid < 13312) { src = Wq; dst = wqkv;              idx = bid - 12288; }
  else if (bid < 14336) { src = Wk; dst = wqkv + (1u << 20); idx = bid - 13312; }
  else if (bid < 15360) { src = Wv; dst = wqkv + (2u << 20); idx = bid - 14336; }
  else                  { src = Wo; dst = wob;               idx = bid - 15360; }
  const int i = idx * 256 + threadIdx.x;
  float4 x = reinterpret_cast<const float4*>(src)[i];
  bf16x4 o;
  o[0] = (bf16)x.x; o[1] = (bf16)x.y; o[2] = (bf16)x.z; o[3] = (bf16)x.w;
  reinterpret_cast<bf16x4*>(dst)[i] = o;
}

// ---------------------------------------------------------------- GEMM (B^T)
// C[i,j] = sum_k A[i,k] * W[j,k] + bias[j],  K=1024, BK=32, 256 thr = 4 waves.
// BM=128/WC=2: waves 2x2 (64x64 each). BM=64/WC=4: waves 1x4 (64x32 each).
// QKV: A/bias/out selected per 1024-col section (fused QKV projection;
// outputs land in three separate [4096][1024] buffers).
template <int BM, int WC, bool QKV, bool F32OUT>
__global__ __launch_bounds__(256) void gemm_bt(
    const bf16* __restrict__ A0, const bf16* __restrict__ A1, const bf16* __restrict__ A2,
    const bf16* __restrict__ W,
    const float* __restrict__ b0, const float* __restrict__ b1, const float* __restrict__ b2,
    bf16* __restrict__ o0, bf16* __restrict__ o1, bf16* __restrict__ o2,
    float* __restrict__ of32) {
  constexpr int K = 1024;
  constexpr int NFR = 128 / (16 * WC);   // N-frags per wave
  constexpr int ACH = BM / 16;           // A staging chunks (1KB each)
  constexpr int NCH = (ACH + 8) / 4;     // staging iterations per wave
  __shared__ bf16 As[BM * 32];
  __shared__ bf16 Bs[128 * 32];

  const int tid = threadIdx.x;
  const int w = tid >> 6, lane = tid & 63;
  const int wr = (WC == 2) ? (w >> 1) : 0;
  const int wc = (WC == 2) ? (w & 1) : w;
  const int row0 = blockIdx.y * BM, col0 = blockIdx.x * 128;

  const int sec = QKV ? (col0 >> 10) : 0;
  const bf16* A    = QKV ? (sec == 0 ? A0 : sec == 1 ? A1 : A2) : A0;
  const float* bias= QKV ? (sec == 0 ? b0 : sec == 1 ? b1 : b2) : b0;
  bf16* outb       = QKV ? (sec == 0 ? o0 : sec == 1 ? o1 : o2) : o0;
  const int cols0  = col0 & 1023;        // col offset within section
  const bf16* Ab = A + (size_t)row0 * K;
  const bf16* Wb = W + (size_t)col0 * K; // wqkv rows indexed by GLOBAL col

  f32x4 acc[4][NFR] = {};

  for (int kt = 0; kt < K / 32; ++kt) {
    const int k0 = kt * 32;
#pragma unroll
    for (int i = 0; i < NCH; ++i) {
      const int cc = i * 4 + w;
      const int rl = lane >> 2;
      const int ce = (lane & 3) * 8;
      if (cc < ACH) {
        const int r = cc * 16 + rl;
        gld_lds16(Ab + (size_t)r * K + k0 + ce, (char*)As + cc * 1024);
      } else {
        const int r = (cc - ACH) * 16 + rl;
        gld_lds16(Wb + (size_t)r * K + k0 + ce, (char*)Bs + (cc - ACH) * 1024);
      }
    }
    __syncthreads();

    bf16x8 af[4], bfr[NFR];
#pragma unroll
    for (int m = 0; m < 4; ++m) {
      const int r = wr * 64 + m * 16 + (lane & 15);
      af[m] = *(const bf16x8*)&As[r * 32 + (lane >> 4) * 8];
    }
#pragma unroll
    for (int n = 0; n < NFR; ++n) {
      const int r = wc * (16 * NFR) + n * 16 + (lane & 15);
      bfr[n] = *(const bf16x8*)&Bs[r * 32 + (lane >> 4) * 8];
    }
#pragma unroll
    for (int m = 0; m < 4; ++m)
#pragma unroll
      for (int n = 0; n < NFR; ++n)
        acc[m][n] = MFMA(af[m], bfr[n], acc[m][n]);
    __syncthreads();
  }

  // epilogue: C/D layout col=lane&15, row=(lane>>4)*4+reg
  const int g = lane >> 4, c15 = lane & 15;
#pragma unroll
  for (int n = 0; n < NFR; ++n) {
    const int col = cols0 + wc * (16 * NFR) + n * 16 + c15;
    const float bv = bias[col];
#pragma unroll
    for (int m = 0; m < 4; ++m) {
      const int rbase = row0 + wr * 64 + m * 16 + g * 4;
#pragma unroll
      for (int r = 0; r < 4; ++r) {
        const float v = acc[m][n][r] + bv;
        if (F32OUT) of32[(size_t)(rbase + r) * 1024 + col] = v;
        else        outb[(size_t)(rbase + r) * 1024 + col] = (bf16)v;
      }
    }
  }
}

// ---------------------------------------------------------------- attention
// VERBATIM from passing Round-10 (paired q-tiles, 512 balanced blocks).
__global__ __launch_bounds__(256) void attn_fwd(
    const bf16* __restrict__ Q, const bf16* __restrict__ K,
    const bf16* __restrict__ V, bf16* __restrict__ X) {
  __shared__ bf16 Ks[2][64][32];
  __shared__ bf16 Vs[2][64][32];
  __shared__ bf16 Ps[4][16][64];

  const int tid = threadIdx.x;
  const int w = tid >> 6, lane = tid & 63;
  const int z = blockIdx.x & 15, bh = blockIdx.x >> 4;
  const int b = bh >> 4, h = bh & 15;

  const bf16* Qb = Q + (size_t)b * Ss * Dd + h * DKk;
  const bf16* Kb = K + (size_t)b * Ss * Dd + h * DKk;
  const bf16* Vb = V + (size_t)b * Ss * Dd + h * DKk;
  bf16* Xb = X + (size_t)b * Ss * Dd + h * DKk;

  for (int pass = 0; pass < 2; ++pass) {
    const int qt = pass ? z : 31 - z;
    const int q0 = qt * 64;

    bf16x8 qf[2];
    {
      const int qr = q0 + w * 16 + (lane & 15);
      const int d0 = (lane >> 4) * 8;
      qf[0] = *(const bf16x8*)&Qb[(size_t)qr * Dd + d0];
      qf[1] = *(const bf16x8*)&Qb[(size_t)qr * Dd + d0 + 32];
    }

    f32x4 of[4] = {};
    float m_run[4], l_run[4];
#pragma unroll
    for (int r = 0; r < 4; ++r) { m_run[r] = -INFINITY; l_run[r] = 0.f; }

    const int nchunks = qt + 1;
    for (int ct = 0; ct < nchunks; ++ct) {
      const int kv0 = ct * 64;
#pragma unroll
      for (int i = 0; i < 2; ++i) {
        const int c = i * 4 + w;
        const int ks = c >> 2;
        const int kvl = (c & 3) * 16 + (lane >> 2);
        const int dl = (lane & 3) * 8;
        gld_lds16(Kb + (size_t)(kv0 + kvl) * Dd + ks * 32 + dl,
                  (char*)Ks + c * 1024);
      }
      {
        const int p = tid >> 3;
        const int d0 = (tid & 7) * 8;
        const int kv = 2 * p;
        const int kh = kv >> 5, kvlo = kv & 31;
        bf16x8 v0 = *(const bf16x8*)&Vb[(size_t)(kv0 + kv) * Dd + d0];
        bf16x8 v1 = *(const bf16x8*)&Vb[(size_t)(kv0 + kv + 1) * Dd + d0];
#pragma unroll
        for (int j = 0; j < 8; ++j) {
          bf16* dst = &Vs[kh][d0 + j][kvlo];
          dst[0] = v0[j];
          dst[1] = v1[j];
        }
      }
      __syncthreads();

      f32x4 sf[4] = {};
#pragma unroll
      for (int n = 0; n < 4; ++n) {
#pragma unroll
        for (int ks = 0; ks < 2; ++ks) {
          bf16x8 kf = *(const bf16x8*)&Ks[ks][n * 16 + (lane & 15)][(lane >> 4) * 8];
          sf[n] = MFMA(qf[ks], kf, sf[n]);
        }
      }

      const int qrb = q0 + w * 16 + (lane >> 4) * 4;
      float mchunk[4];
#pragma unroll
      for (int r = 0; r < 4; ++r) mchunk[r] = -INFINITY;
#pragma unroll
      for (int n = 0; n < 4; ++n) {
        const int kvcol = kv0 + n * 16 + (lane & 15);
#pragma unroll
        for (int r = 0; r < 4; ++r) {
          float sv = sf[n][r] * 0.125f;
          if (kvcol > qrb + r) sv = -INFINITY;
          sf[n][r] = sv;
          mchunk[r] = fmaxf(mchunk[r], sv);
        }
      }
#pragma unroll
      for (int off = 1; off < 16; off <<= 1)
#pragma unroll
        for (int r = 0; r < 4; ++r)
          mchunk[r] = fmaxf(mchunk[r], __shfl_xor(mchunk[r], off, 64));

      float alpha[4], rsum[4];
#pragma unroll
      for (int r = 0; r < 4; ++r) {
        const float mn = fmaxf(m_run[r], mchunk[r]);
        alpha[r] = __expf(m_run[r] - mn);
        m_run[r] = mn;
        rsum[r] = 0.f;
      }
#pragma unroll
      for (int n = 0; n < 4; ++n)
#pragma unroll
        for (int r = 0; r < 4; ++r) {
          const float p = __expf(sf[n][r] - m_run[r]);
          rsum[r] += p;
          Ps[w][(lane >> 4) * 4 + r][n * 16 + (lane & 15)] = (bf16)p;
        }
#pragma unroll
      for (int off = 1; off < 16; off <<= 1)
#pragma unroll
        for (int r = 0; r < 4; ++r)
          rsum[r] += __shfl_xor(rsum[r], off, 64);
#pragma unroll
      for (int r = 0; r < 4; ++r)
        l_run[r] = l_run[r] * alpha[r] + rsum[r];
#pragma unroll
      for (int n = 0; n < 4; ++n)
#pragma unroll
        for (int r = 0; r < 4; ++r)
          of[n][r] *= alpha[r];

#pragma unroll
      for (int ks = 0; ks < 2; ++ks) {
        bf16x8 pfr = *(const bf16x8*)&Ps[w][lane & 15][ks * 32 + (lane >> 4) * 8];
#pragma unroll
        for (int n = 0; n < 4; ++n) {
          bf16x8 vf = *(const bf16x8*)&Vs[ks][n * 16 + (lane & 15)][(lane >> 4) * 8];
          of[n] = MFMA(pfr, vf, of[n]);
        }
      }
      __syncthreads();
    }

#pragma unroll
    for (int n = 0; n < 4; ++n)
#pragma unroll
      for (int r = 0; r < 4; ++r) {
        const int q = q0 + w * 16 + (lane >> 4) * 4 + r;
        const float v = of[n][r] / l_run[r];
        Xb[(size_t)q * Dd + n * 16 + (lane & 15)] = (bf16)v;
      }
  }
}

// ---------------------------------------------------------------- launch
extern "C" void kernel_launch(void* const* d_in, const int* in_sizes, int n_in,
                              void* d_out, int out_size, void* d_ws, size_t ws_size,
                              hipStream_t stream) {
  const float* query = (const float*)d_in[0];
  const float* key   = (const float*)d_in[1];
  const float* value = (const float*)d_in[2];
  // d_in[3] = mask: tril by construction; causal handled analytically
  const float* Wq = (const float*)d_in[4];
  const float* bq = (const float*)d_in[5];
  const float* Wk = (const float*)d_in[6];
  const float* bk = (const float*)d_in[7];
  const float* Wv = (const float*)d_in[8];
  const float* bv = (const float*)d_in[9];
  const float* Wo = (const float*)d_in[10];
  const float* bo = (const float*)d_in[11];

  char* ws = (char*)d_ws;
  bf16* qb   = (bf16*)(ws + (0ull  << 20));
  bf16* kb   = (bf16*)(ws + (8ull  << 20));
  bf16* vb   = (bf16*)(ws + (16ull << 20));
  bf16* wqkv = (bf16*)(ws + (24ull << 20));
  bf16* wob  = (bf16*)(ws + (30ull << 20));
  bf16* Qp   = (bf16*)(ws + (32ull << 20));
  bf16* Kp   = (bf16*)(ws + (40ull << 20));
  bf16* Vp   = (bf16*)(ws + (48ull << 20));
  bf16* Xa   = (bf16*)(ws + (56ull << 20));

  prep<<<16384, 256, 0, stream>>>(query, key, value, Wq, Wk, Wv, Wo,
                                  qb, kb, vb, wqkv, wob);

  // fused QKV projection: N=3072 over packed wqkv, per-section A/bias/out
  gemm_bt<128, 2, true, false><<<dim3(24, 32), 256, 0, stream>>>(
      qb, kb, vb, wqkv, bq, bk, bv, Qp, Kp, Vp, nullptr);

  attn_fwd<<<512, 256, 0, stream>>>(Qp, Kp, Vp, Xa);

  // output projection: BM=64 tiles -> 512 blocks (2 blocks/CU)
  gemm_bt<64, 4, false, true><<<dim3(8, 64), 256, 0, stream>>>(
      Xa, nullptr, nullptr, wob, bo, nullptr, nullptr,
      nullptr, nullptr, nullptr, (float*)d_out);
}